// Round 2
// baseline (274.195 us; speedup 1.0000x reference)
//
#include <hip/hip_runtime.h>
#include <hip/hip_bf16.h>
#include <stdint.h>

typedef unsigned short u16;
typedef unsigned int u32;
typedef __attribute__((ext_vector_type(8))) short bf16x8;
typedef __attribute__((ext_vector_type(4))) float f32x4;

#define S_DIM 2048
#define D_DIM 1024
#define TM 128
#define TN 128
#define BK 64

// float -> bf16 round-to-nearest-even
__device__ __forceinline__ u16 f2bf(float f) {
  u32 u = __float_as_uint(f);
  u += 0x7FFFu + ((u >> 16) & 1u);
  return (u16)(u >> 16);
}

typedef const __attribute__((address_space(1))) u32* gas1p;
typedef __attribute__((address_space(3))) u32* las3p;

// async global->LDS, 16B per lane; LDS dest is wave-uniform base + lane*16
__device__ __forceinline__ void gload_lds16(const void* g, void* l) {
  __builtin_amdgcn_global_load_lds((gas1p)g, (las3p)l, 16, 0, 0);
}

// ---------------------------------------------------------------------------
// prep: x(f32) -> Q=bf16(x), K=bf16(x*wl*wr), Vt=bf16(x)^T ; zero lsum
// tile 64(t) x 64(d) per block, 256 threads
// ---------------------------------------------------------------------------
__global__ __launch_bounds__(256) void prep_kernel(
    const float* __restrict__ x, const float* __restrict__ wl,
    const float* __restrict__ wr, u16* __restrict__ Qb, u16* __restrict__ Kb,
    u16* __restrict__ Vt, float* __restrict__ lsum, int batch0) {
  const int S = S_DIM, D = D_DIM;
  int nz = blockIdx.z;
  const float* xb = x + (size_t)(batch0 + nz) * S * D;
  u16* Qn = Qb + (size_t)nz * S * D;
  u16* Kn = Kb + (size_t)nz * S * D;
  u16* Vn = Vt + (size_t)nz * D * S;
  int t0 = blockIdx.x * 64;
  int d0 = blockIdx.y * 64;
  int tid = threadIdx.x;
  int rl = tid >> 4;         // 0..15
  int cl = (tid & 15) << 2;  // 0..60 step 4

  if (blockIdx.y == 0 && tid < 64) lsum[(size_t)nz * S + t0 + tid] = 0.0f;

  __shared__ u16 ldsT[64][68];  // [d_local][t_local], padded

  float4 a = *(const float4*)(wl + d0 + cl);
  float4 b = *(const float4*)(wr + d0 + cl);
  float wv0 = a.x * b.x, wv1 = a.y * b.y, wv2 = a.z * b.z, wv3 = a.w * b.w;

#pragma unroll
  for (int p = 0; p < 4; ++p) {
    int r = p * 16 + rl;
    float4 xv = *(const float4*)(xb + (size_t)(t0 + r) * D + d0 + cl);
    u16 q0 = f2bf(xv.x), q1 = f2bf(xv.y), q2 = f2bf(xv.z), q3 = f2bf(xv.w);
    u16 k0 = f2bf(xv.x * wv0), k1 = f2bf(xv.y * wv1);
    u16 k2 = f2bf(xv.z * wv2), k3 = f2bf(xv.w * wv3);
    uint2 qpk;
    qpk.x = (u32)q0 | ((u32)q1 << 16);
    qpk.y = (u32)q2 | ((u32)q3 << 16);
    *(uint2*)(Qn + (size_t)(t0 + r) * D + d0 + cl) = qpk;
    uint2 kpk;
    kpk.x = (u32)k0 | ((u32)k1 << 16);
    kpk.y = (u32)k2 | ((u32)k3 << 16);
    *(uint2*)(Kn + (size_t)(t0 + r) * D + d0 + cl) = kpk;
    ldsT[cl + 0][r] = q0;
    ldsT[cl + 1][r] = q1;
    ldsT[cl + 2][r] = q2;
    ldsT[cl + 3][r] = q3;
  }
  __syncthreads();
#pragma unroll
  for (int p = 0; p < 4; ++p) {
    int dr = p * 16 + rl;
    u16 v0 = ldsT[dr][cl + 0], v1 = ldsT[dr][cl + 1];
    u16 v2 = ldsT[dr][cl + 2], v3 = ldsT[dr][cl + 3];
    uint2 pk;
    pk.x = (u32)v0 | ((u32)v1 << 16);
    pk.y = (u32)v2 | ((u32)v3 << 16);
    *(uint2*)(Vn + (size_t)(d0 + dr) * S + t0 + cl) = pk;
  }
}

// ---------------------------------------------------------------------------
// GEMM1: P = exp(min(Q @ K^T, 30)) (bf16), lsum[row] += row-sums (atomic)
// 128x128 tile, 4 waves (2x2), each 64x64 via 4x4 16x16x32 bf16 MFMA, BK=64.
// global_load_lds w=16, both-sides XOR swizzle (seg ^= row&7) for bank spread.
// ---------------------------------------------------------------------------
__global__ __launch_bounds__(256, 2) void qk_exp_kernel(
    const u16* __restrict__ Qb, const u16* __restrict__ Kb,
    u16* __restrict__ P, float* __restrict__ lsum) {
  const int S = S_DIM, D = D_DIM;
  int nz = blockIdx.z;
  const u16* A = Qb + (size_t)nz * S * D;
  const u16* B = Kb + (size_t)nz * S * D;
  u16* C = P + (size_t)nz * S * S;
  float* lrow = lsum + (size_t)nz * S;

  int m0 = blockIdx.x * TM;
  int n0 = blockIdx.y * TN;
  int tid = threadIdx.x;
  int wave = tid >> 6;
  int lane = tid & 63;
  int lk = lane & 15;
  int g8 = lane >> 4;
  int wr = (wave >> 1) * 64;
  int wc = (wave & 1) * 64;

  __shared__ __align__(16) u16 As[TM * BK];
  __shared__ __align__(16) u16 Bs[TN * BK];

  // staging: chunk ci = wave*4+q covers rows ci*8..ci*8+7 (1KB per chunk)
  int srow = (wave << 5) + (lane >> 3);
  int skel = ((lane & 7) ^ (lane >> 3)) << 3;  // pre-swizzled k element offset
  const u16* gA = A + (size_t)(m0 + srow) * D + skel;
  const u16* gB = B + (size_t)(n0 + srow) * D + skel;

  int sx = (lane & 7) << 4;  // read-side XOR (bytes)
  int aoff[4], boff[4];
#pragma unroll
  for (int i = 0; i < 4; ++i) {
    aoff[i] = ((wr + i * 16 + lk) * BK + g8 * 8) * 2;
    boff[i] = ((wc + i * 16 + lk) * BK + g8 * 8) * 2;
  }

  f32x4 acc[4][4] = {};

  for (int k0 = 0; k0 < D; k0 += BK) {
#pragma unroll
    for (int q = 0; q < 4; ++q) {
      gload_lds16(gA + (size_t)q * 8 * D, As + (wave * 4 + q) * 512);
      gload_lds16(gB + (size_t)q * 8 * D, Bs + (wave * 4 + q) * 512);
    }
    gA += BK;
    gB += BK;
    __syncthreads();
#pragma unroll
    for (int kk = 0; kk < 2; ++kk) {
      bf16x8 af[4], bfr[4];
#pragma unroll
      for (int i = 0; i < 4; ++i)
        af[i] = *(const bf16x8*)((const char*)As + ((aoff[i] + kk * 64) ^ sx));
#pragma unroll
      for (int i = 0; i < 4; ++i)
        bfr[i] = *(const bf16x8*)((const char*)Bs + ((boff[i] + kk * 64) ^ sx));
#pragma unroll
      for (int i = 0; i < 4; ++i)
#pragma unroll
        for (int j = 0; j < 4; ++j)
          acc[i][j] = __builtin_amdgcn_mfma_f32_16x16x32_bf16(af[i], bfr[j],
                                                              acc[i][j], 0, 0, 0);
    }
    __syncthreads();
  }

  int rr = g8 << 2;
  // exp(min(s,30)) in place
#pragma unroll
  for (int i = 0; i < 4; ++i)
#pragma unroll
    for (int j = 0; j < 4; ++j)
#pragma unroll
      for (int r = 0; r < 4; ++r)
        acc[i][j][r] = __expf(fminf(acc[i][j][r], 30.0f));

  // store P (bf16): C layout col=lane&15, row=(lane>>4)*4+reg
#pragma unroll
  for (int i = 0; i < 4; ++i) {
#pragma unroll
    for (int r = 0; r < 4; ++r) {
      size_t row = (size_t)(m0 + wr + i * 16 + rr + r);
      u16* cp = C + row * S + n0 + wc + lk;
      cp[0] = f2bf(acc[i][0][r]);
      cp[16] = f2bf(acc[i][1][r]);
      cp[32] = f2bf(acc[i][2][r]);
      cp[48] = f2bf(acc[i][3][r]);
    }
  }

  // per-row partial sums over this block's 128 cols -> atomicAdd
#pragma unroll
  for (int i = 0; i < 4; ++i) {
    f32x4 rs = acc[i][0] + acc[i][1] + acc[i][2] + acc[i][3];
#pragma unroll
    for (int d = 1; d < 16; d <<= 1) {
      rs[0] += __shfl_xor(rs[0], d);
      rs[1] += __shfl_xor(rs[1], d);
      rs[2] += __shfl_xor(rs[2], d);
      rs[3] += __shfl_xor(rs[3], d);
    }
    if (lk == 0) {
#pragma unroll
      for (int r = 0; r < 4; ++r)
        atomicAdd(&lrow[m0 + wr + i * 16 + rr + r], rs[r]);
    }
  }
}

// ---------------------------------------------------------------------------
// GEMM2: out = (P @ V) / lsum  (fp32 out). B^T input = Vt [d][t]. K = S.
// ---------------------------------------------------------------------------
__global__ __launch_bounds__(256, 2) void pv_kernel(
    const u16* __restrict__ P, const u16* __restrict__ Vt,
    const float* __restrict__ lsum, float* __restrict__ out) {
  const int S = S_DIM, D = D_DIM;
  int nz = blockIdx.z;
  const u16* A = P + (size_t)nz * S * S;
  const u16* B = Vt + (size_t)nz * D * S;
  const float* lrow = lsum + (size_t)nz * S;
  float* Cn = out + (size_t)nz * S * D;

  int m0 = blockIdx.x * TM;
  int n0 = blockIdx.y * TN;
  int tid = threadIdx.x;
  int wave = tid >> 6;
  int lane = tid & 63;
  int lk = lane & 15;
  int g8 = lane >> 4;
  int wr = (wave >> 1) * 64;
  int wc = (wave & 1) * 64;

  __shared__ __align__(16) u16 As[TM * BK];
  __shared__ __align__(16) u16 Bs[TN * BK];

  int srow = (wave << 5) + (lane >> 3);
  int skel = ((lane & 7) ^ (lane >> 3)) << 3;
  const u16* gA = A + (size_t)(m0 + srow) * S + skel;
  const u16* gB = B + (size_t)(n0 + srow) * S + skel;

  int sx = (lane & 7) << 4;
  int aoff[4], boff[4];
#pragma unroll
  for (int i = 0; i < 4; ++i) {
    aoff[i] = ((wr + i * 16 + lk) * BK + g8 * 8) * 2;
    boff[i] = ((wc + i * 16 + lk) * BK + g8 * 8) * 2;
  }

  f32x4 acc[4][4] = {};

  for (int k0 = 0; k0 < S; k0 += BK) {
#pragma unroll
    for (int q = 0; q < 4; ++q) {
      gload_lds16(gA + (size_t)q * 8 * S, As + (wave * 4 + q) * 512);
      gload_lds16(gB + (size_t)q * 8 * S, Bs + (wave * 4 + q) * 512);
    }
    gA += BK;
    gB += BK;
    __syncthreads();
#pragma unroll
    for (int kk = 0; kk < 2; ++kk) {
      bf16x8 af[4], bfr[4];
#pragma unroll
      for (int i = 0; i < 4; ++i)
        af[i] = *(const bf16x8*)((const char*)As + ((aoff[i] + kk * 64) ^ sx));
#pragma unroll
      for (int i = 0; i < 4; ++i)
        bfr[i] = *(const bf16x8*)((const char*)Bs + ((boff[i] + kk * 64) ^ sx));
#pragma unroll
      for (int i = 0; i < 4; ++i)
#pragma unroll
        for (int j = 0; j < 4; ++j)
          acc[i][j] = __builtin_amdgcn_mfma_f32_16x16x32_bf16(af[i], bfr[j],
                                                              acc[i][j], 0, 0, 0);
    }
    __syncthreads();
  }

  int rr = g8 << 2;
#pragma unroll
  for (int i = 0; i < 4; ++i) {
#pragma unroll
    for (int r = 0; r < 4; ++r) {
      int row = m0 + wr + i * 16 + rr + r;
      float inv = __fdividef(1.0f, lrow[row]);
      float* cp = Cn + (size_t)row * D + n0 + wc + lk;
      cp[0] = acc[i][0][r] * inv;
      cp[16] = acc[i][1][r] * inv;
      cp[32] = acc[i][2][r] * inv;
      cp[48] = acc[i][3][r] * inv;
    }
  }
}

// ---------------------------------------------------------------------------
extern "C" void kernel_launch(void* const* d_in, const int* in_sizes, int n_in,
                              void* d_out, int out_size, void* d_ws,
                              size_t ws_size, hipStream_t stream) {
  const float* x = (const float*)d_in[0];
  const float* wl = (const float*)d_in[1];
  const float* wr = (const float*)d_in[2];
  float* out = (float*)d_out;
  const int N = 8, S = S_DIM, D = D_DIM;
  const size_t szQ = (size_t)S * D;  // elements per batch (Q/K/Vt each)
  const size_t szP = (size_t)S * S;

  // batch group size that fits the workspace: g*(3*Q + P)*2B + g*S*4B
  int g = 8;
  while (g > 1) {
    size_t need = (size_t)g * (3 * szQ * 2 + szP * 2 + (size_t)S * 4);
    if (need <= ws_size) break;
    g >>= 1;
  }

  for (int b0 = 0; b0 < N; b0 += g) {
    u16* Qb = (u16*)d_ws;
    u16* Kb = Qb + (size_t)g * szQ;
    u16* Vt = Kb + (size_t)g * szQ;
    u16* Pp = Vt + (size_t)g * szQ;
    float* lsum = (float*)(Pp + (size_t)g * szP);
    hipLaunchKernelGGL(prep_kernel, dim3(S / 64, D / 64, g), dim3(256), 0,
                       stream, x, wl, wr, Qb, Kb, Vt, lsum, b0);
    hipLaunchKernelGGL(qk_exp_kernel, dim3(S / TM, S / TN, g), dim3(256), 0,
                       stream, Qb, Kb, Pp, lsum);
    hipLaunchKernelGGL(pv_kernel, dim3(S / TM, D / TN, g), dim3(256), 0,
                       stream, Pp, Vt, lsum, out + (size_t)b0 * S * D);
  }
}

// Round 3
// 270.706 us; speedup vs baseline: 1.0129x; 1.0129x over previous
//
#include <hip/hip_runtime.h>
#include <hip/hip_bf16.h>
#include <stdint.h>

typedef unsigned short u16;
typedef unsigned int u32;
typedef __attribute__((ext_vector_type(8))) short bf16x8;
typedef __attribute__((ext_vector_type(4))) float f32x4;

#define S_DIM 2048
#define D_DIM 1024

// float -> bf16 round-to-nearest-even
__device__ __forceinline__ u16 f2bf(float f) {
  u32 u = __float_as_uint(f);
  u += 0x7FFFu + ((u >> 16) & 1u);
  return (u16)(u >> 16);
}

typedef const __attribute__((address_space(1))) u32* gas1p;
typedef __attribute__((address_space(3))) u32* las3p;

// async global->LDS, 16B per lane; LDS dest is wave-uniform base + lane*16
__device__ __forceinline__ void gload_lds16(const void* g, void* l) {
  __builtin_amdgcn_global_load_lds((gas1p)g, (las3p)l, 16, 0, 0);
}

__device__ __forceinline__ void mfma16(f32x4& c, bf16x8 a, bf16x8 b) {
  c = __builtin_amdgcn_mfma_f32_16x16x32_bf16(a, b, c, 0, 0, 0);
}

// ---------------------------------------------------------------------------
// prep: x(f32) -> Q=bf16(x), K=bf16(x*wl*wr), Vt=bf16(x)^T ; zero lsum
// ---------------------------------------------------------------------------
__global__ __launch_bounds__(256) void prep_kernel(
    const float* __restrict__ x, const float* __restrict__ wl,
    const float* __restrict__ wr, u16* __restrict__ Qb, u16* __restrict__ Kb,
    u16* __restrict__ Vt, float* __restrict__ lsum, int batch0) {
  const int S = S_DIM, D = D_DIM;
  int nz = blockIdx.z;
  const float* xb = x + (size_t)(batch0 + nz) * S * D;
  u16* Qn = Qb + (size_t)nz * S * D;
  u16* Kn = Kb + (size_t)nz * S * D;
  u16* Vn = Vt + (size_t)nz * D * S;
  int t0 = blockIdx.x * 64;
  int d0 = blockIdx.y * 64;
  int tid = threadIdx.x;
  int rl = tid >> 4;         // 0..15
  int cl = (tid & 15) << 2;  // 0..60 step 4

  if (blockIdx.y == 0 && tid < 64) lsum[(size_t)nz * S + t0 + tid] = 0.0f;

  __shared__ u16 ldsT[64][68];  // [d_local][t_local], padded

  float4 a = *(const float4*)(wl + d0 + cl);
  float4 b = *(const float4*)(wr + d0 + cl);
  float wv0 = a.x * b.x, wv1 = a.y * b.y, wv2 = a.z * b.z, wv3 = a.w * b.w;

#pragma unroll
  for (int p = 0; p < 4; ++p) {
    int r = p * 16 + rl;
    float4 xv = *(const float4*)(xb + (size_t)(t0 + r) * D + d0 + cl);
    u16 q0 = f2bf(xv.x), q1 = f2bf(xv.y), q2 = f2bf(xv.z), q3 = f2bf(xv.w);
    u16 k0 = f2bf(xv.x * wv0), k1 = f2bf(xv.y * wv1);
    u16 k2 = f2bf(xv.z * wv2), k3 = f2bf(xv.w * wv3);
    uint2 qpk;
    qpk.x = (u32)q0 | ((u32)q1 << 16);
    qpk.y = (u32)q2 | ((u32)q3 << 16);
    *(uint2*)(Qn + (size_t)(t0 + r) * D + d0 + cl) = qpk;
    uint2 kpk;
    kpk.x = (u32)k0 | ((u32)k1 << 16);
    kpk.y = (u32)k2 | ((u32)k3 << 16);
    *(uint2*)(Kn + (size_t)(t0 + r) * D + d0 + cl) = kpk;
    ldsT[cl + 0][r] = q0;
    ldsT[cl + 1][r] = q1;
    ldsT[cl + 2][r] = q2;
    ldsT[cl + 3][r] = q3;
  }
  __syncthreads();
#pragma unroll
  for (int p = 0; p < 4; ++p) {
    int dr = p * 16 + rl;
    u16 v0 = ldsT[dr][cl + 0], v1 = ldsT[dr][cl + 1];
    u16 v2 = ldsT[dr][cl + 2], v3 = ldsT[dr][cl + 3];
    uint2 pk;
    pk.x = (u32)v0 | ((u32)v1 << 16);
    pk.y = (u32)v2 | ((u32)v3 << 16);
    *(uint2*)(Vn + (size_t)(d0 + dr) * S + t0 + cl) = pk;
  }
}

// ---------------------------------------------------------------------------
// 256x256-tile multi-phase GEMM main loop (T3+T4+T5), C = A @ B^T pattern.
// 8 waves (2M x 4N), per-wave 128x64 output, BK=64, 128 KiB LDS dbuf.
// 4 phases/K-tile: {ds_read subtile | stage 1 half-tile | barrier |
//                   lgkmcnt(0) | setprio(1) 16xMFMA setprio(0) | barrier},
// one counted vmcnt(2) per K-tile (phase 3), drained only at the tail.
// LDS swizzle: both-sides XOR (G[row][seg^(row&7)] staged linearly,
// reads XOR (lane&7) on the 16B segment) -- measured 0 bank conflicts.
// ---------------------------------------------------------------------------
__device__ __forceinline__ void gemm_main(const u16* __restrict__ A,
                                          const u16* __restrict__ B, int m0,
                                          int n0, int ldk, int NT, char* cl,
                                          int tid, f32x4 (&acc)[8][4]) {
  int lane = tid & 63, w = tid >> 6;
  int lk = lane & 15, g8 = lane >> 4, l7 = lane & 7;
  int wr = w >> 2, wc = w & 3;
  int sA0 = (wr * 128 + lk) * 128;          // A row byte base (m=0)
  int sB0 = (wc * 64 + lk) * 128 + 32768;   // B row byte base (n=0)
  int sx0 = (g8 ^ l7) << 4;                 // kk=0 swizzled seg byte
  int sx1 = ((4 + g8) ^ l7) << 4;           // kk=1
  int r8 = lane >> 3;                       // 0..7 row-in-chunk
  int kel = (l7 ^ r8) << 3;                 // pre-swizzled k element offset
  const u16* gAs = A + (size_t)(m0 + w * 16 + r8) * ldk + kel;
  const u16* gBs = B + (size_t)(n0 + w * 16 + r8) * ldk + kel;
  char* dA = cl + w * 2048;
  char* dB = cl + 32768 + w * 2048;

#define STG_A(kt_, h_, b_)                                                  \
  {                                                                         \
    const u16* g_ = gAs + (size_t)(kt_)*64 + (size_t)(h_)*128 * ldk;        \
    char* d_ = dA + (b_)*65536 + (h_)*16384;                                \
    gload_lds16(g_, d_);                                                    \
    gload_lds16(g_ + 8 * (size_t)ldk, d_ + 1024);                           \
  }
#define STG_B(kt_, h_, b_)                                                  \
  {                                                                         \
    const u16* g_ = gBs + (size_t)(kt_)*64 + (size_t)(h_)*128 * ldk;        \
    char* d_ = dB + (b_)*65536 + (h_)*16384;                                \
    gload_lds16(g_, d_);                                                    \
    gload_lds16(g_ + 8 * (size_t)ldk, d_ + 1024);                           \
  }

  // prologue: tile0 (4 halves) + A(1)h0; wait tile0 (leave 1 half in flight)
  STG_A(0, 0, 0);
  STG_A(0, 1, 0);
  STG_B(0, 0, 0);
  STG_B(0, 1, 0);
  STG_A(1, 0, 1);
  asm volatile("s_waitcnt vmcnt(2)");
  __builtin_amdgcn_s_barrier();

  bf16x8 af0[4][2], af1[4][2], bfr[2][2];

#pragma unroll 1
  for (int kt = 0; kt < NT; ++kt) {
    int b = kt & 1, nb = b ^ 1;
    int bo = b * 65536;
    // ---- phase 0: read A m0-3 + B n0-1; stage A(kt+1)h1; MFMA q(0,0)
#pragma unroll
    for (int m = 0; m < 4; ++m) {
      af0[m][0] = *(const bf16x8*)(cl + bo + sA0 + m * 2048 + sx0);
      af0[m][1] = *(const bf16x8*)(cl + bo + sA0 + m * 2048 + sx1);
    }
#pragma unroll
    for (int n = 0; n < 2; ++n) {
      bfr[n][0] = *(const bf16x8*)(cl + bo + sB0 + n * 2048 + sx0);
      bfr[n][1] = *(const bf16x8*)(cl + bo + sB0 + n * 2048 + sx1);
    }
    if (kt + 1 < NT) STG_A(kt + 1, 1, nb);
    __builtin_amdgcn_s_barrier();
    asm volatile("s_waitcnt lgkmcnt(0)");
    __builtin_amdgcn_s_setprio(1);
#pragma unroll
    for (int m = 0; m < 4; ++m)
#pragma unroll
      for (int n = 0; n < 2; ++n) {
        mfma16(acc[m][n], af0[m][0], bfr[n][0]);
        mfma16(acc[m][n], af0[m][1], bfr[n][1]);
      }
    __builtin_amdgcn_s_setprio(0);
    __builtin_amdgcn_s_barrier();
    // ---- phase 1: read A m4-7; stage B(kt+1)h0; MFMA q(1,0)
#pragma unroll
    for (int m = 0; m < 4; ++m) {
      af1[m][0] = *(const bf16x8*)(cl + bo + sA0 + (m + 4) * 2048 + sx0);
      af1[m][1] = *(const bf16x8*)(cl + bo + sA0 + (m + 4) * 2048 + sx1);
    }
    if (kt + 1 < NT) STG_B(kt + 1, 0, nb);
    __builtin_amdgcn_s_barrier();
    asm volatile("s_waitcnt lgkmcnt(0)");
    __builtin_amdgcn_s_setprio(1);
#pragma unroll
    for (int m = 0; m < 4; ++m)
#pragma unroll
      for (int n = 0; n < 2; ++n) {
        mfma16(acc[m + 4][n], af1[m][0], bfr[n][0]);
        mfma16(acc[m + 4][n], af1[m][1], bfr[n][1]);
      }
    __builtin_amdgcn_s_setprio(0);
    __builtin_amdgcn_s_barrier();
    // ---- phase 2: read B n2-3; stage B(kt+1)h1; MFMA q(0,1)
#pragma unroll
    for (int n = 0; n < 2; ++n) {
      bfr[n][0] = *(const bf16x8*)(cl + bo + sB0 + (n + 2) * 2048 + sx0);
      bfr[n][1] = *(const bf16x8*)(cl + bo + sB0 + (n + 2) * 2048 + sx1);
    }
    if (kt + 1 < NT) STG_B(kt + 1, 1, nb);
    __builtin_amdgcn_s_barrier();
    asm volatile("s_waitcnt lgkmcnt(0)");
    __builtin_amdgcn_s_setprio(1);
#pragma unroll
    for (int m = 0; m < 4; ++m)
#pragma unroll
      for (int n = 0; n < 2; ++n) {
        mfma16(acc[m][n + 2], af0[m][0], bfr[n][0]);
        mfma16(acc[m][n + 2], af0[m][1], bfr[n][1]);
      }
    __builtin_amdgcn_s_setprio(0);
    __builtin_amdgcn_s_barrier();
    // ---- phase 3: stage A(kt+2)h0 (into just-freed buf b); MFMA q(1,1);
    //              counted vmcnt releases tile kt+1
    if (kt + 2 < NT) STG_A(kt + 2, 0, b);
    __builtin_amdgcn_s_barrier();
    asm volatile("s_waitcnt lgkmcnt(0)");
    __builtin_amdgcn_s_setprio(1);
#pragma unroll
    for (int m = 0; m < 4; ++m)
#pragma unroll
      for (int n = 0; n < 2; ++n) {
        mfma16(acc[m + 4][n + 2], af1[m][0], bfr[n][0]);
        mfma16(acc[m + 4][n + 2], af1[m][1], bfr[n][1]);
      }
    __builtin_amdgcn_s_setprio(0);
    if (kt + 2 < NT) {
      asm volatile("s_waitcnt vmcnt(2)");
    } else {
      asm volatile("s_waitcnt vmcnt(0)");
    }
    __builtin_amdgcn_s_barrier();
  }
#undef STG_A
#undef STG_B
}

// ---------------------------------------------------------------------------
// GEMM1: P = exp(min(Q @ K^T, 30)) (bf16), lsum[row] += row-sums (atomic)
// ---------------------------------------------------------------------------
__global__ __launch_bounds__(512, 2) void qk_exp_kernel(
    const u16* __restrict__ Qb, const u16* __restrict__ Kb,
    u16* __restrict__ P, float* __restrict__ lsum) {
  const int S = S_DIM, D = D_DIM;
  int nz = blockIdx.z;
  const u16* A = Qb + (size_t)nz * S * D;
  const u16* B = Kb + (size_t)nz * S * D;
  u16* C = P + (size_t)nz * S * S;
  float* lrow = lsum + (size_t)nz * S;

  int m0 = blockIdx.x * 256;
  int n0 = blockIdx.y * 256;
  int tid = threadIdx.x;

  __shared__ __align__(16) u16 lds[65536];  // 128 KiB
  f32x4 acc[8][4] = {};
  gemm_main(A, B, m0, n0, D, D / 64, (char*)lds, tid, acc);

  int lane = tid & 63, w = tid >> 6;
  int lk = lane & 15, g8 = lane >> 4;
  int wr = w >> 2, wc = w & 3;
  int rr = g8 << 2;
#pragma unroll
  for (int m = 0; m < 8; ++m) {
    int rowb = m0 + wr * 128 + m * 16 + rr;
    float rs[4] = {0.f, 0.f, 0.f, 0.f};
#pragma unroll
    for (int n = 0; n < 4; ++n) {
#pragma unroll
      for (int r = 0; r < 4; ++r) {
        float e = __expf(fminf(acc[m][n][r], 30.0f));
        rs[r] += e;
        C[(size_t)(rowb + r) * S + n0 + wc * 64 + n * 16 + lk] = f2bf(e);
      }
    }
#pragma unroll
    for (int d = 1; d < 16; d <<= 1) {
      rs[0] += __shfl_xor(rs[0], d);
      rs[1] += __shfl_xor(rs[1], d);
      rs[2] += __shfl_xor(rs[2], d);
      rs[3] += __shfl_xor(rs[3], d);
    }
    if (lk == 0) {
#pragma unroll
      for (int r = 0; r < 4; ++r) atomicAdd(&lrow[rowb + r], rs[r]);
    }
  }
}

// ---------------------------------------------------------------------------
// GEMM2: out = (P @ V) / lsum  (fp32 out). B^T input = Vt [d][t]. K = S.
// ---------------------------------------------------------------------------
__global__ __launch_bounds__(512, 2) void pv_kernel(
    const u16* __restrict__ P, const u16* __restrict__ Vt,
    const float* __restrict__ lsum, float* __restrict__ out) {
  const int S = S_DIM, D = D_DIM;
  int nz = blockIdx.z;
  const u16* A = P + (size_t)nz * S * S;
  const u16* B = Vt + (size_t)nz * D * S;
  const float* lrow = lsum + (size_t)nz * S;
  float* Cn = out + (size_t)nz * S * D;

  int m0 = blockIdx.x * 256;
  int n0 = blockIdx.y * 256;
  int tid = threadIdx.x;

  __shared__ __align__(16) u16 lds[65536];  // 128 KiB
  f32x4 acc[8][4] = {};
  gemm_main(A, B, m0, n0, S, S / 64, (char*)lds, tid, acc);

  int lane = tid & 63, w = tid >> 6;
  int lk = lane & 15, g8 = lane >> 4;
  int wr = w >> 2, wc = w & 3;
  int rr = g8 << 2;
#pragma unroll
  for (int m = 0; m < 8; ++m) {
    int rowb = m0 + wr * 128 + m * 16 + rr;
#pragma unroll
    for (int r = 0; r < 4; ++r) {
      float inv = __fdividef(1.0f, lrow[rowb + r]);
      float* cp = Cn + (size_t)(rowb + r) * D + n0 + wc * 64 + lk;
      cp[0] = acc[m][0][r] * inv;
      cp[16] = acc[m][1][r] * inv;
      cp[32] = acc[m][2][r] * inv;
      cp[48] = acc[m][3][r] * inv;
    }
  }
}

// ---------------------------------------------------------------------------
extern "C" void kernel_launch(void* const* d_in, const int* in_sizes, int n_in,
                              void* d_out, int out_size, void* d_ws,
                              size_t ws_size, hipStream_t stream) {
  const float* x = (const float*)d_in[0];
  const float* wl = (const float*)d_in[1];
  const float* wr = (const float*)d_in[2];
  float* out = (float*)d_out;
  const int N = 8, S = S_DIM, D = D_DIM;
  const size_t szQ = (size_t)S * D;
  const size_t szP = (size_t)S * S;

  // batch group size that fits the workspace: g*(3*Q + P)*2B + g*S*4B
  int g = 8;
  while (g > 1) {
    size_t need = (size_t)g * (3 * szQ * 2 + szP * 2 + (size_t)S * 4);
    if (need <= ws_size) break;
    g >>= 1;
  }

  for (int b0 = 0; b0 < N; b0 += g) {
    u16* Qb = (u16*)d_ws;
    u16* Kb = Qb + (size_t)g * szQ;
    u16* Vt = Kb + (size_t)g * szQ;
    u16* Pp = Vt + (size_t)g * szQ;
    float* lsum = (float*)(Pp + (size_t)g * szP);
    hipLaunchKernelGGL(prep_kernel, dim3(S / 64, D / 64, g), dim3(256), 0,
                       stream, x, wl, wr, Qb, Kb, Vt, lsum, b0);
    hipLaunchKernelGGL(qk_exp_kernel, dim3(S / 256, S / 256, g), dim3(512), 0,
                       stream, Qb, Kb, Pp, lsum);
    hipLaunchKernelGGL(pv_kernel, dim3(S / 256, D / 256, g), dim3(512), 0,
                       stream, Pp, Vt, lsum, out + (size_t)b0 * S * D);
  }
}

// Round 5
// 255.307 us; speedup vs baseline: 1.0740x; 1.0603x over previous
//
#include <hip/hip_runtime.h>
#include <hip/hip_bf16.h>
#include <stdint.h>

typedef unsigned short u16;
typedef unsigned int u32;
typedef __attribute__((ext_vector_type(8))) short bf16x8;
typedef __attribute__((ext_vector_type(4))) float f32x4;

#define S_DIM 2048
#define D_DIM 1024

// float -> bf16 round-to-nearest-even
__device__ __forceinline__ u16 f2bf(float f) {
  u32 u = __float_as_uint(f);
  u += 0x7FFFu + ((u >> 16) & 1u);
  return (u16)(u >> 16);
}

typedef const __attribute__((address_space(1))) u32* gas1p;
typedef __attribute__((address_space(3))) u32* las3p;

// async global->LDS, 16B per lane; LDS dest is wave-uniform base + lane*16
__device__ __forceinline__ void gload_lds16(const void* g, void* l) {
  __builtin_amdgcn_global_load_lds((gas1p)g, (las3p)l, 16, 0, 0);
}

__device__ __forceinline__ void mfma16(f32x4& c, bf16x8 a, bf16x8 b) {
  c = __builtin_amdgcn_mfma_f32_16x16x32_bf16(a, b, c, 0, 0, 0);
}

// ---------------------------------------------------------------------------
// prep: x(f32) -> Q=bf16(x), K=bf16(x*wl*wr), Vt=bf16(x)^T ; zero lsum
// ---------------------------------------------------------------------------
__global__ __launch_bounds__(256) void prep_kernel(
    const float* __restrict__ x, const float* __restrict__ wl,
    const float* __restrict__ wr, u16* __restrict__ Qb, u16* __restrict__ Kb,
    u16* __restrict__ Vt, float* __restrict__ lsum, int batch0) {
  const int S = S_DIM, D = D_DIM;
  int nz = blockIdx.z;
  const float* xb = x + (size_t)(batch0 + nz) * S * D;
  u16* Qn = Qb + (size_t)nz * S * D;
  u16* Kn = Kb + (size_t)nz * S * D;
  u16* Vn = Vt + (size_t)nz * D * S;
  int t0 = blockIdx.x * 64;
  int d0 = blockIdx.y * 64;
  int tid = threadIdx.x;
  int rl = tid >> 4;         // 0..15
  int cl = (tid & 15) << 2;  // 0..60 step 4

  if (blockIdx.y == 0 && tid < 64) lsum[(size_t)nz * S + t0 + tid] = 0.0f;

  __shared__ u16 ldsT[64][68];  // [d_local][t_local], padded

  float4 a = *(const float4*)(wl + d0 + cl);
  float4 b = *(const float4*)(wr + d0 + cl);
  float wv0 = a.x * b.x, wv1 = a.y * b.y, wv2 = a.z * b.z, wv3 = a.w * b.w;

#pragma unroll
  for (int p = 0; p < 4; ++p) {
    int r = p * 16 + rl;
    float4 xv = *(const float4*)(xb + (size_t)(t0 + r) * D + d0 + cl);
    u16 q0 = f2bf(xv.x), q1 = f2bf(xv.y), q2 = f2bf(xv.z), q3 = f2bf(xv.w);
    u16 k0 = f2bf(xv.x * wv0), k1 = f2bf(xv.y * wv1);
    u16 k2 = f2bf(xv.z * wv2), k3 = f2bf(xv.w * wv3);
    uint2 qpk;
    qpk.x = (u32)q0 | ((u32)q1 << 16);
    qpk.y = (u32)q2 | ((u32)q3 << 16);
    *(uint2*)(Qn + (size_t)(t0 + r) * D + d0 + cl) = qpk;
    uint2 kpk;
    kpk.x = (u32)k0 | ((u32)k1 << 16);
    kpk.y = (u32)k2 | ((u32)k3 << 16);
    *(uint2*)(Kn + (size_t)(t0 + r) * D + d0 + cl) = kpk;
    ldsT[cl + 0][r] = q0;
    ldsT[cl + 1][r] = q1;
    ldsT[cl + 2][r] = q2;
    ldsT[cl + 3][r] = q3;
  }
  __syncthreads();
#pragma unroll
  for (int p = 0; p < 4; ++p) {
    int dr = p * 16 + rl;
    u16 v0 = ldsT[dr][cl + 0], v1 = ldsT[dr][cl + 1];
    u16 v2 = ldsT[dr][cl + 2], v3 = ldsT[dr][cl + 3];
    uint2 pk;
    pk.x = (u32)v0 | ((u32)v1 << 16);
    pk.y = (u32)v2 | ((u32)v3 << 16);
    *(uint2*)(Vn + (size_t)(d0 + dr) * S + t0 + cl) = pk;
  }
}

// ---------------------------------------------------------------------------
// 256x256-tile GEMM main loop, C = A @ B^T pattern.
// 8 waves (2M x 4N), per-wave 128x64 output, BK=64, 128 KiB LDS dbuf.
// ONE barrier + ONE vmcnt(0) per K-tile: stages for kt+1 issue at tile top
// (into the other buffer), whole-tile ds_reads + 64 MFMA run in a
// barrier-free region (compiler emits counted lgkmcnt; kk=1 reads drain
// under kk=0 MFMA pass), boundary vmcnt(0)+barrier publishes the stages.
// LDS swizzle: both-sides XOR (G[row][seg^(row&7)] staged linearly,
// reads XOR (row&7) on the 16B segment) -- measured 0 bank conflicts.
// ---------------------------------------------------------------------------
__device__ __forceinline__ void gemm_main(const u16* __restrict__ A,
                                          const u16* __restrict__ B, int m0,
                                          int n0, int ldk, int NT, char* cl,
                                          int tid, f32x4 (&acc)[8][4]) {
  int lane = tid & 63, w = tid >> 6;
  int lk = lane & 15, g8 = lane >> 4, l7 = lane & 7;
  int wr = w >> 2, wc = w & 3;
  int sA0 = (wr * 128 + lk) * 128;         // A row byte base (m=0)
  int sB0 = (wc * 64 + lk) * 128 + 32768;  // B row byte base (n=0)
  int sx0 = (g8 ^ l7) << 4;                // kk=0 swizzled seg byte
  int sx1 = ((4 + g8) ^ l7) << 4;          // kk=1
  int r8 = lane >> 3;                      // 0..7 row-in-chunk
  int kel = (l7 ^ r8) << 3;                // pre-swizzled k element offset
  const u16* gAs = A + (size_t)(m0 + w * 16 + r8) * ldk + kel;
  const u16* gBs = B + (size_t)(n0 + w * 16 + r8) * ldk + kel;
  char* dA = cl + w * 2048;
  char* dB = cl + 32768 + w * 2048;

  // stage all 4 half-tiles (A h0,h1 + B h0,h1) of K-tile kt_ into buffer b_
#define STG_ALL(kt_, b_)                                   \
  {                                                        \
    const u16* ga_ = gAs + (size_t)(kt_)*64;               \
    const u16* gb_ = gBs + (size_t)(kt_)*64;               \
    char* da_ = dA + (b_)*65536;                           \
    char* db_ = dB + (b_)*65536;                           \
    gload_lds16(ga_, da_);                                 \
    gload_lds16(ga_ + 8 * (size_t)ldk, da_ + 1024);        \
    gload_lds16(ga_ + 128 * (size_t)ldk, da_ + 16384);     \
    gload_lds16(ga_ + 136 * (size_t)ldk, da_ + 17408);     \
    gload_lds16(gb_, db_);                                 \
    gload_lds16(gb_ + 8 * (size_t)ldk, db_ + 1024);        \
    gload_lds16(gb_ + 128 * (size_t)ldk, db_ + 16384);     \
    gload_lds16(gb_ + 136 * (size_t)ldk, db_ + 17408);     \
  }

  // prologue: stage tile 0 into buf 0, publish
  STG_ALL(0, 0);
  asm volatile("s_waitcnt vmcnt(0)");
  __builtin_amdgcn_s_barrier();

#pragma unroll 1
  for (int kt = 0; kt < NT; ++kt) {
    int b = kt & 1;
    int bo = b * 65536;
    if (kt + 1 < NT) STG_ALL(kt + 1, b ^ 1);

    bf16x8 a0[8], a1[8], b0[4], b1[4];
#pragma unroll
    for (int m = 0; m < 8; ++m)
      a0[m] = *(const bf16x8*)(cl + bo + sA0 + m * 2048 + sx0);
#pragma unroll
    for (int n = 0; n < 4; ++n)
      b0[n] = *(const bf16x8*)(cl + bo + sB0 + n * 2048 + sx0);
#pragma unroll
    for (int m = 0; m < 8; ++m)
      a1[m] = *(const bf16x8*)(cl + bo + sA0 + m * 2048 + sx1);
#pragma unroll
    for (int n = 0; n < 4; ++n)
      b1[n] = *(const bf16x8*)(cl + bo + sB0 + n * 2048 + sx1);

    __builtin_amdgcn_s_setprio(1);
#pragma unroll
    for (int m = 0; m < 8; ++m)
#pragma unroll
      for (int n = 0; n < 4; ++n) mfma16(acc[m][n], a0[m], b0[n]);
#pragma unroll
    for (int m = 0; m < 8; ++m)
#pragma unroll
      for (int n = 0; n < 4; ++n) mfma16(acc[m][n], a1[m], b1[n]);
    __builtin_amdgcn_s_setprio(0);

    asm volatile("s_waitcnt vmcnt(0)");
    __builtin_amdgcn_s_barrier();
  }
#undef STG_ALL
}

// ---------------------------------------------------------------------------
// GEMM1: P = exp(min(Q @ K^T, 30)) (bf16), lsum[row] += row-sums (atomic)
// ---------------------------------------------------------------------------
__global__ __launch_bounds__(512, 2) void qk_exp_kernel(
    const u16* __restrict__ Qb, const u16* __restrict__ Kb,
    u16* __restrict__ P, float* __restrict__ lsum) {
  const int S = S_DIM, D = D_DIM;
  // bijective XCD swizzle: grid (8,8,gz), nwg = 64*gz (always %8==0)
  int gz = gridDim.z;
  int lid = blockIdx.x + (blockIdx.y << 3) + (blockIdx.z << 6);
  int cpx = gz << 3;
  int swz = (lid & 7) * cpx + (lid >> 3);
  int bx = swz & 7, by = (swz >> 3) & 7, bz = swz >> 6;

  const u16* A = Qb + (size_t)bz * S * D;
  const u16* B = Kb + (size_t)bz * S * D;
  u16* C = P + (size_t)bz * S * S;
  float* lrow = lsum + (size_t)bz * S;

  int m0 = bx * 256;
  int n0 = by * 256;
  int tid = threadIdx.x;

  __shared__ __align__(16) u16 lds[65536];  // 128 KiB
  f32x4 acc[8][4] = {};
  gemm_main(A, B, m0, n0, D, D / 64, (char*)lds, tid, acc);

  int lane = tid & 63, w = tid >> 6;
  int lk = lane & 15, g8 = lane >> 4;
  int wr = w >> 2, wc = w & 3;
  int rr = g8 << 2;
#pragma unroll
  for (int m = 0; m < 8; ++m) {
    int rowb = m0 + wr * 128 + m * 16 + rr;
    float rs[4] = {0.f, 0.f, 0.f, 0.f};
#pragma unroll
    for (int n = 0; n < 4; ++n) {
#pragma unroll
      for (int r = 0; r < 4; ++r) {
        float e = __expf(fminf(acc[m][n][r], 30.0f));
        rs[r] += e;
        C[(size_t)(rowb + r) * S + n0 + wc * 64 + n * 16 + lk] = f2bf(e);
      }
    }
#pragma unroll
    for (int d = 1; d < 16; d <<= 1) {
      rs[0] += __shfl_xor(rs[0], d);
      rs[1] += __shfl_xor(rs[1], d);
      rs[2] += __shfl_xor(rs[2], d);
      rs[3] += __shfl_xor(rs[3], d);
    }
    if (lk == 0) {
#pragma unroll
      for (int r = 0; r < 4; ++r) atomicAdd(&lrow[rowb + r], rs[r]);
    }
  }
}

// ---------------------------------------------------------------------------
// GEMM2: out = (P @ V) / lsum  (fp32 out). B^T input = Vt [d][t]. K = S.
// ---------------------------------------------------------------------------
__global__ __launch_bounds__(512, 2) void pv_kernel(
    const u16* __restrict__ P, const u16* __restrict__ Vt,
    const float* __restrict__ lsum, float* __restrict__ out) {
  const int S = S_DIM, D = D_DIM;
  // bijective XCD swizzle: grid (8,4,gz), nwg = 32*gz (always %8==0)
  int gz = gridDim.z;
  int lid = blockIdx.x + (blockIdx.y << 3) + (blockIdx.z << 5);
  int cpx = gz << 2;
  int swz = (lid & 7) * cpx + (lid >> 3);
  int bx = swz & 7, by = (swz >> 3) & 3, bz = swz >> 5;

  const u16* A = P + (size_t)bz * S * S;
  const u16* B = Vt + (size_t)bz * D * S;
  const float* lrow = lsum + (size_t)bz * S;
  float* Cn = out + (size_t)bz * S * D;

  int m0 = bx * 256;
  int n0 = by * 256;
  int tid = threadIdx.x;

  __shared__ __align__(16) u16 lds[65536];  // 128 KiB
  f32x4 acc[8][4] = {};
  gemm_main(A, B, m0, n0, S, S / 64, (char*)lds, tid, acc);

  int lane = tid & 63, w = tid >> 6;
  int lk = lane & 15, g8 = lane >> 4;
  int wr = w >> 2, wc = w & 3;
  int rr = g8 << 2;
#pragma unroll
  for (int m = 0; m < 8; ++m) {
    int rowb = m0 + wr * 128 + m * 16 + rr;
#pragma unroll
    for (int r = 0; r < 4; ++r) {
      float inv = __fdividef(1.0f, lrow[rowb + r]);
      float* cp = Cn + (size_t)(rowb + r) * D + n0 + wc * 64 + lk;
      cp[0] = acc[m][0][r] * inv;
      cp[16] = acc[m][1][r] * inv;
      cp[32] = acc[m][2][r] * inv;
      cp[48] = acc[m][3][r] * inv;
    }
  }
}

// ---------------------------------------------------------------------------
extern "C" void kernel_launch(void* const* d_in, const int* in_sizes, int n_in,
                              void* d_out, int out_size, void* d_ws,
                              size_t ws_size, hipStream_t stream) {
  const float* x = (const float*)d_in[0];
  const float* wl = (const float*)d_in[1];
  const float* wr = (const float*)d_in[2];
  float* out = (float*)d_out;
  const int N = 8, S = S_DIM, D = D_DIM;
  const size_t szQ = (size_t)S * D;
  const size_t szP = (size_t)S * S;

  // batch group size that fits the workspace: g*(3*Q + P)*2B + g*S*4B
  int g = 8;
  while (g > 1) {
    size_t need = (size_t)g * (3 * szQ * 2 + szP * 2 + (size_t)S * 4);
    if (need <= ws_size) break;
    g >>= 1;
  }

  for (int b0 = 0; b0 < N; b0 += g) {
    u16* Qb = (u16*)d_ws;
    u16* Kb = Qb + (size_t)g * szQ;
    u16* Vt = Kb + (size_t)g * szQ;
    u16* Pp = Vt + (size_t)g * szQ;
    float* lsum = (float*)(Pp + (size_t)g * szP);
    hipLaunchKernelGGL(prep_kernel, dim3(S / 64, D / 64, g), dim3(256), 0,
                       stream, x, wl, wr, Qb, Kb, Vt, lsum, b0);
    hipLaunchKernelGGL(qk_exp_kernel, dim3(S / 256, S / 256, g), dim3(512), 0,
                       stream, Qb, Kb, Pp, lsum);
    hipLaunchKernelGGL(pv_kernel, dim3(S / 256, D / 256, g), dim3(512), 0,
                       stream, Pp, Vt, lsum, out + (size_t)b0 * S * D);
  }
}